// Round 7
// baseline (158.188 us; speedup 1.0000x reference)
//
#include <hip/hip_runtime.h>
#include <hip/hip_bf16.h>

#define S_   8
#define N_   1024
#define KG_  16
#define MW_  64
#define CI_  128
#define CO_  256

typedef __attribute__((ext_vector_type(8))) short bf16x8;
typedef __attribute__((ext_vector_type(4))) float f32x4;

// ---------------------------------------------------------------------------
// Fused: W fp32->bf16 convert + circular sliding-window sums (bf16 out).
// win[s][t][c] = sum_{m<64} x[s][(t+m)%N][c]
// ---------------------------------------------------------------------------
__global__ __launch_bounds__(256) void win_kernel(const float* __restrict__ x,
                                                  const float* __restrict__ W,
                                                  __hip_bfloat16* __restrict__ win,
                                                  __hip_bfloat16* __restrict__ Wb) {
    __shared__ float lds[96][CI_];           // 48 KB
    const int b   = blockIdx.x;              // 0..255
    const int tid = threadIdx.x;

    // --- W conversion: 8 elems per thread ---
    {
        const int wi = (b * 256 + tid) * 8;
        const float4 v0 = *(const float4*)&W[wi];
        const float4 v1 = *(const float4*)&W[wi + 4];
        union { unsigned short u[8]; uint4 v; } o;
        __hip_bfloat16 h;
        h = __float2bfloat16(v0.x); o.u[0] = *(unsigned short*)&h;
        h = __float2bfloat16(v0.y); o.u[1] = *(unsigned short*)&h;
        h = __float2bfloat16(v0.z); o.u[2] = *(unsigned short*)&h;
        h = __float2bfloat16(v0.w); o.u[3] = *(unsigned short*)&h;
        h = __float2bfloat16(v1.x); o.u[4] = *(unsigned short*)&h;
        h = __float2bfloat16(v1.y); o.u[5] = *(unsigned short*)&h;
        h = __float2bfloat16(v1.z); o.u[6] = *(unsigned short*)&h;
        h = __float2bfloat16(v1.w); o.u[7] = *(unsigned short*)&h;
        *(uint4*)&Wb[wi] = o.v;
    }

    // --- sliding window ---
    const int s   = b >> 5;
    const int t0  = (b & 31) << 5;           // 32 t's per block
    const float* xs = x + (size_t)s * N_ * CI_;

    for (int e = tid * 4; e < 96 * CI_; e += 256 * 4) {
        const int r = e >> 7;
        const int c = e & (CI_ - 1);
        *(float4*)&lds[r][c] = *(const float4*)&xs[((t0 + r) & (N_ - 1)) * CI_ + c];
    }
    __syncthreads();

    const int c  = tid & (CI_ - 1);
    const int tb = (tid >> 7) << 4;          // 0 or 16
    float s0 = 0.f, s1 = 0.f, s2 = 0.f, s3 = 0.f;
    #pragma unroll
    for (int m = 0; m < MW_; m += 4) {
        s0 += lds[tb + m + 0][c];
        s1 += lds[tb + m + 1][c];
        s2 += lds[tb + m + 2][c];
        s3 += lds[tb + m + 3][c];
    }
    float w = (s0 + s1) + (s2 + s3);
    __hip_bfloat16* wo = win + (size_t)s * N_ * CI_;
    wo[(t0 + tb) * CI_ + c] = __float2bfloat16(w);
    #pragma unroll
    for (int t = 1; t < 16; ++t) {
        w += lds[tb + t - 1 + MW_][c] - lds[tb + t - 1][c];
        wo[(t0 + tb + t) * CI_ + c] = __float2bfloat16(w);
    }
}

// ---------------------------------------------------------------------------
// out[s,n,o] = sum_{g,c} win[s,(n+64g)%N,c] * W[g,o,c]
// LDS-FREE register MFMA GEMM. One wave per block; wave owns a 64x64 output
// tile (4x4 frags of 16x16x32 bf16, fp32 acc). Fragments are 16B-contiguous
// in global memory, loaded directly to VGPRs (global_load_dwordx4) with
// 1-step ping-pong prefetch. No LDS, no barriers, no waitcnt choreography.
// Grid 512 blocks (2 waves/CU); XCD-pinned: s = blockIdx.x & 7 so each XCD's
// 64 blocks share win[s] (256KB) + W (1MB) in its local L2.
// A-frag: lane l: row (n0+g*64 + i*16 + (l&15)) & 1023, k = (l>>4)*8..+8
// B-frag: lane l: row  o0 + j*16 + (l&15) of W[g],      k = (l>>4)*8..+8
// (identical operand layouts to the LDS version validated rounds 2-5)
// ---------------------------------------------------------------------------
#define KT 64      // K32 steps: K=2048 = 64 * 32

__global__ __launch_bounds__(64) void gemm_kernel(const __hip_bfloat16* __restrict__ winb,
                                                  const __hip_bfloat16* __restrict__ Wb,
                                                  float* __restrict__ out) {
    const int l   = threadIdx.x;             // 0..63
    const int s   = blockIdx.x & 7;          // XCD-pinned sample index
    const int rem = blockIdx.x >> 3;         // 0..63
    const int n0  = (rem & 15) << 6;         // 64-row tile
    const int o0  = (rem >> 4) << 6;         // 64-col tile

    const int fr = l & 15;
    const int kq = l >> 4;                   // 0..3

    const unsigned short* winp = (const unsigned short*)winb + (size_t)s * N_ * CI_;
    const unsigned short* Wp   = (const unsigned short*)Wb;

    f32x4 acc[4][4];
    #pragma unroll
    for (int i = 0; i < 4; ++i)
        #pragma unroll
        for (int j = 0; j < 4; ++j)
            acc[i][j] = f32x4{0.f, 0.f, 0.f, 0.f};

    auto load_step = [&](int t, bf16x8* a, bf16x8* b) {
        const int g    = t >> 2;             // group 0..15
        const int koff = ((t & 3) << 5) + kq * 8;   // k offset within CI
        const int nb   = n0 + (g << 6) + fr;
        #pragma unroll
        for (int i = 0; i < 4; ++i) {
            const int row = (nb + i * 16) & (N_ - 1);
            a[i] = *(const bf16x8*)&winp[row * CI_ + koff];
        }
        const unsigned short* wg = Wp + ((g * CO_ + o0 + fr) * CI_) + koff;
        #pragma unroll
        for (int j = 0; j < 4; ++j)
            b[j] = *(const bf16x8*)&wg[j * 16 * CI_];
    };

    bf16x8 a0[4], b0[4], a1[4], b1[4];
    load_step(0, a0, b0);

    for (int t = 0; t < KT; t += 2) {
        load_step(t + 1, a1, b1);            // prefetch odd step
        #pragma unroll
        for (int i = 0; i < 4; ++i)
            #pragma unroll
            for (int j = 0; j < 4; ++j)
                acc[i][j] = __builtin_amdgcn_mfma_f32_16x16x32_bf16(a0[i], b0[j], acc[i][j], 0, 0, 0);
        if (t + 2 < KT) load_step(t + 2, a0, b0);   // prefetch next even step
        #pragma unroll
        for (int i = 0; i < 4; ++i)
            #pragma unroll
            for (int j = 0; j < 4; ++j)
                acc[i][j] = __builtin_amdgcn_mfma_f32_16x16x32_bf16(a1[i], b1[j], acc[i][j], 0, 0, 0);
    }

    // D layout: col = lane&15, row = (lane>>4)*4 + reg (validated r2-r5)
    float* op = out + ((size_t)(s * N_ + n0) * CO_) + o0;
    #pragma unroll
    for (int i = 0; i < 4; ++i)
        #pragma unroll
        for (int j = 0; j < 4; ++j)
            #pragma unroll
            for (int r = 0; r < 4; ++r)
                op[(i * 16 + kq * 4 + r) * CO_ + j * 16 + fr] = acc[i][j][r];
}

extern "C" void kernel_launch(void* const* d_in, const int* in_sizes, int n_in,
                              void* d_out, int out_size, void* d_ws, size_t ws_size,
                              hipStream_t stream) {
    const float* x = (const float*)d_in[0];   // [S, N, CI]
    const float* W = (const float*)d_in[1];   // [K, CO, CI]

    __hip_bfloat16* winb = (__hip_bfloat16*)d_ws;                               // 2 MB
    __hip_bfloat16* Wbb  = (__hip_bfloat16*)((char*)d_ws +
                              (size_t)S_ * N_ * CI_ * sizeof(__hip_bfloat16));  // 1 MB
    float* out = (float*)d_out;               // [S, N, CO] fp32

    win_kernel<<<256, 256, 0, stream>>>(x, W, winb, Wbb);

    // Launched TWICE on purpose (idempotent full overwrite): the delta vs
    // round 5 separates gemm time from the fixed harness window exactly.
    gemm_kernel<<<512, 64, 0, stream>>>(winb, Wbb, out);
    gemm_kernel<<<512, 64, 0, stream>>>(winb, Wbb, out);
}

// Round 8
// 98.499 us; speedup vs baseline: 1.6060x; 1.6060x over previous
//
#include <hip/hip_runtime.h>
#include <hip/hip_bf16.h>

#define S_   8
#define N_   1024
#define KG_  16
#define MW_  64
#define CI_  128
#define CO_  256

typedef __attribute__((ext_vector_type(8))) short bf16x8;
typedef __attribute__((ext_vector_type(4))) float f32x4;

// ---------------------------------------------------------------------------
// Fused: W fp32->bf16 convert + circular sliding-window sums (bf16 out).
// win[s][t][c] = sum_{m<64} x[s][(t+m)%N][c]
// ---------------------------------------------------------------------------
__global__ __launch_bounds__(256) void win_kernel(const float* __restrict__ x,
                                                  const float* __restrict__ W,
                                                  __hip_bfloat16* __restrict__ win,
                                                  __hip_bfloat16* __restrict__ Wb) {
    __shared__ float lds[96][CI_];           // 48 KB
    const int b   = blockIdx.x;              // 0..255
    const int tid = threadIdx.x;

    // --- W conversion: 8 elems per thread ---
    {
        const int wi = (b * 256 + tid) * 8;
        const float4 v0 = *(const float4*)&W[wi];
        const float4 v1 = *(const float4*)&W[wi + 4];
        union { unsigned short u[8]; uint4 v; } o;
        __hip_bfloat16 h;
        h = __float2bfloat16(v0.x); o.u[0] = *(unsigned short*)&h;
        h = __float2bfloat16(v0.y); o.u[1] = *(unsigned short*)&h;
        h = __float2bfloat16(v0.z); o.u[2] = *(unsigned short*)&h;
        h = __float2bfloat16(v0.w); o.u[3] = *(unsigned short*)&h;
        h = __float2bfloat16(v1.x); o.u[4] = *(unsigned short*)&h;
        h = __float2bfloat16(v1.y); o.u[5] = *(unsigned short*)&h;
        h = __float2bfloat16(v1.z); o.u[6] = *(unsigned short*)&h;
        h = __float2bfloat16(v1.w); o.u[7] = *(unsigned short*)&h;
        *(uint4*)&Wb[wi] = o.v;
    }

    // --- sliding window ---
    const int s   = b >> 5;
    const int t0  = (b & 31) << 5;           // 32 t's per block
    const float* xs = x + (size_t)s * N_ * CI_;

    for (int e = tid * 4; e < 96 * CI_; e += 256 * 4) {
        const int r = e >> 7;
        const int c = e & (CI_ - 1);
        *(float4*)&lds[r][c] = *(const float4*)&xs[((t0 + r) & (N_ - 1)) * CI_ + c];
    }
    __syncthreads();

    const int c  = tid & (CI_ - 1);
    const int tb = (tid >> 7) << 4;          // 0 or 16
    float s0 = 0.f, s1 = 0.f, s2 = 0.f, s3 = 0.f;
    #pragma unroll
    for (int m = 0; m < MW_; m += 4) {
        s0 += lds[tb + m + 0][c];
        s1 += lds[tb + m + 1][c];
        s2 += lds[tb + m + 2][c];
        s3 += lds[tb + m + 3][c];
    }
    float w = (s0 + s1) + (s2 + s3);
    __hip_bfloat16* wo = win + (size_t)s * N_ * CI_;
    wo[(t0 + tb) * CI_ + c] = __float2bfloat16(w);
    #pragma unroll
    for (int t = 1; t < 16; ++t) {
        w += lds[tb + t - 1 + MW_][c] - lds[tb + t - 1][c];
        wo[(t0 + tb + t) * CI_ + c] = __float2bfloat16(w);
    }
}

// ---------------------------------------------------------------------------
// out[s,n,o] = sum_{g,c} win[s,(n+64g)%N,c] * W[g,o,c]
// Register MFMA GEMM with K-SPLIT x4.  Block = 256 threads (4 waves), tile
// 64x64; wave w handles groups w*4..w*4+3 (K=512, 16 K32-steps), 4x4 frags
// of 16x16x32 bf16, direct global->VGPR loads, 4-deep static prefetch.
// Partials reduced via 4 separate LDS buffers + one barrier (no RMW chains).
// Grid 512 blocks = 2 blocks/CU = 8 waves/CU (TLP hides L2/HBM latency).
// XCD-pinned: s = blockIdx.x & 7.
// ---------------------------------------------------------------------------
__global__ __launch_bounds__(256, 2) void gemm_kernel(const __hip_bfloat16* __restrict__ winb,
                                                      const __hip_bfloat16* __restrict__ Wb,
                                                      float* __restrict__ out) {
    __shared__ __align__(16) float red[4][64][68];   // 69.6 KB

    const int tid = threadIdx.x;
    const int l   = tid & 63;
    const int wv  = tid >> 6;                // 0..3
    const int s   = blockIdx.x & 7;          // XCD-pinned sample index
    const int rem = blockIdx.x >> 3;         // 0..63
    const int n0  = (rem & 15) << 6;         // 64-row tile
    const int o0  = (rem >> 4) << 6;         // 64-col tile

    const int fr  = l & 15;
    const int kq  = l >> 4;                  // 0..3
    const int kq8 = kq * 8;
    const int w4  = wv << 2;                 // first group of this wave

    const unsigned short* winp = (const unsigned short*)winb + (size_t)s * N_ * CI_;
    const unsigned short* Wp   = (const unsigned short*)Wb;

    f32x4 acc[4][4];
    #pragma unroll
    for (int i = 0; i < 4; ++i)
        #pragma unroll
        for (int j = 0; j < 4; ++j)
            acc[i][j] = f32x4{0.f, 0.f, 0.f, 0.f};

    // load step t (0..15): g = w4 + (t>>2), koff = (t&3)*32 + kq*8
    auto load_step = [&](int t, bf16x8* a, bf16x8* b) {
        const int g    = w4 + (t >> 2);
        const int koff = ((t & 3) << 5) + kq8;
        const int nb   = n0 + (g << 6) + fr;
        #pragma unroll
        for (int i = 0; i < 4; ++i) {
            const int row = (nb + i * 16) & (N_ - 1);
            a[i] = *(const bf16x8*)&winp[row * CI_ + koff];
        }
        const unsigned short* wg = Wp + ((g * CO_ + o0 + fr) * CI_) + koff;
        #pragma unroll
        for (int j = 0; j < 4; ++j)
            b[j] = *(const bf16x8*)&wg[j * 16 * CI_];
    };

    bf16x8 A[4][4], B[4][4];                 // [slot][frag] — static idx only
    #pragma unroll
    for (int p = 0; p < 4; ++p) load_step(p, A[p], B[p]);

    // 3 full rounds with prefetch (steps 0..11 compute, 4..15 load) ...
    for (int base = 0; base < 12; base += 4) {
        #pragma unroll
        for (int p = 0; p < 4; ++p) {
            #pragma unroll
            for (int i = 0; i < 4; ++i)
                #pragma unroll
                for (int j = 0; j < 4; ++j)
                    acc[i][j] = __builtin_amdgcn_mfma_f32_16x16x32_bf16(A[p][i], B[p][j], acc[i][j], 0, 0, 0);
            load_step(base + 4 + p, A[p], B[p]);
        }
    }
    // ... final round, no prefetch
    #pragma unroll
    for (int p = 0; p < 4; ++p)
        #pragma unroll
        for (int i = 0; i < 4; ++i)
            #pragma unroll
            for (int j = 0; j < 4; ++j)
                acc[i][j] = __builtin_amdgcn_mfma_f32_16x16x32_bf16(A[p][i], B[p][j], acc[i][j], 0, 0, 0);

    // Each wave stores its partial to its own LDS buffer (stride 68: 2-way max).
    // D layout: col = lane&15, row = (lane>>4)*4 + reg (validated r2-r7)
    #pragma unroll
    for (int i = 0; i < 4; ++i)
        #pragma unroll
        for (int j = 0; j < 4; ++j)
            #pragma unroll
            for (int r = 0; r < 4; ++r)
                red[wv][i * 16 + kq * 4 + r][j * 16 + fr] = acc[i][j][r];

    __syncthreads();

    // Cooperative 4-way sum + coalesced write: thread t -> row t>>2, 16 cols.
    const int r  = tid >> 2;
    const int cb = (tid & 3) << 4;
    float* op = out + ((size_t)(s * N_ + n0 + r) * CO_) + o0 + cb;
    #pragma unroll
    for (int q = 0; q < 4; ++q) {
        const f32x4 v0 = *(const f32x4*)&red[0][r][cb + q * 4];
        const f32x4 v1 = *(const f32x4*)&red[1][r][cb + q * 4];
        const f32x4 v2 = *(const f32x4*)&red[2][r][cb + q * 4];
        const f32x4 v3 = *(const f32x4*)&red[3][r][cb + q * 4];
        const f32x4 v  = (v0 + v1) + (v2 + v3);
        *(f32x4*)&op[q * 4] = v;
    }
}

extern "C" void kernel_launch(void* const* d_in, const int* in_sizes, int n_in,
                              void* d_out, int out_size, void* d_ws, size_t ws_size,
                              hipStream_t stream) {
    const float* x = (const float*)d_in[0];   // [S, N, CI]
    const float* W = (const float*)d_in[1];   // [K, CO, CI]

    __hip_bfloat16* winb = (__hip_bfloat16*)d_ws;                               // 2 MB
    __hip_bfloat16* Wbb  = (__hip_bfloat16*)((char*)d_ws +
                              (size_t)S_ * N_ * CI_ * sizeof(__hip_bfloat16));  // 1 MB
    float* out = (float*)d_out;               // [S, N, CO] fp32

    win_kernel<<<256, 256, 0, stream>>>(x, W, winb, Wbb);
    gemm_kernel<<<512, 256, 0, stream>>>(winb, Wbb, out);
}